// Round 12
// baseline (248.063 us; speedup 1.0000x reference)
//
#include <hip/hip_runtime.h>
#include <math.h>

namespace {
constexpr int B   = 4;
constexpr int C   = 128;
constexpr int H   = 128;
constexpr int W   = 128;
constexpr int HWn = H * W;           // 16384
constexpr int NH  = 8;
}

using short8 = __attribute__((ext_vector_type(8))) short;
using f32x4  = __attribute__((ext_vector_type(4))) float;

__device__ __forceinline__ float fast_tanh(float x) {
  float e = __expf(2.f * x);
  return 1.f - 2.f / (e + 1.f);
}
__device__ __forceinline__ unsigned f2bf(float f) {  // RNE bf16 bits
  unsigned u = __float_as_uint(f);
  return (u + 0x7FFFu + ((u >> 16) & 1u)) >> 16;
}
__device__ __forceinline__ unsigned pack2bf(float a, float b) {
  return f2bf(a) | (f2bf(b) << 16);
}

// ---------------------------------------------------------------------------
// R16 = R15 (=R9) with K1 rebuilt light. K2 is untouched (87.8 us, at its
// scattered-request service-rate floor per R12/R13/R14 evidence).
// K1: 32q strips, 4096 blocks, B-fragments direct from L1-resident weight
// tables (R12-proven pattern), LDS 9.7 KB, unroll 1 on ck (VGPR policy).
// Same ck accumulation order -> bit-identical val and proj.
// ---------------------------------------------------------------------------

// Prep: bf16 transposed weights in ws.
//   wcat_t[192][128]: rows 0..127 = Woff cols, 128..191 = Wattn cols
//   wval_t[128][128], wout_t[128][128] (wout_t[n][k] = Wout[k][n])
__global__ __launch_bounds__(256) void prep_weights_kernel(
    const float* __restrict__ Woff, const float* __restrict__ Wattn,
    const float* __restrict__ Wval, const float* __restrict__ Wout,
    unsigned short* __restrict__ wcat_t, unsigned short* __restrict__ wval_t,
    unsigned short* __restrict__ wout_t) {
  int row = blockIdx.x * 256 + threadIdx.x;
  if (row >= 448) return;
  const float* src; int ldn; int col; unsigned short* dst;
  if (row < 192) {
    if (row < 128) { src = Woff; ldn = 128; col = row; }
    else           { src = Wattn; ldn = 64; col = row - 128; }
    dst = wcat_t + row * 128;
  } else if (row < 320) {
    src = Wval; ldn = 128; col = row - 192; dst = wval_t + (row - 192) * 128;
  } else {
    src = Wout; ldn = 128; col = row - 320; dst = wout_t + (row - 320) * 128;
  }
  for (int k0 = 0; k0 < 128; k0 += 8) {
    unsigned pk[4];
#pragma unroll
    for (int j = 0; j < 4; ++j)
      pk[j] = pack2bf(src[(k0 + 2 * j) * ldn + col],
                      src[(k0 + 2 * j + 1) * ldn + col]);
    *(uint4*)(dst + k0) = make_uint4(pk[0], pk[1], pk[2], pk[3]);
  }
}

// K1 (R16): both GEMMs, 32q strips, 4096 blocks (grp0: val, grp1: proj).
// B-fragments read directly from global weight tables (L1-resident 32/48 KB)
// -- no b_s staging, no per-ck barriers.
__global__ __launch_bounds__(256) void gemm_kernel(
    const float* __restrict__ nbr, const float* __restrict__ ext,
    const unsigned short* __restrict__ wval_t,
    const float* __restrict__ bv,
    const unsigned short* __restrict__ wcat_t,
    const float* __restrict__ boff, const float* __restrict__ battn,
    unsigned short* __restrict__ val, float* __restrict__ proj) {
  __shared__ unsigned short a_s[32 * 152];   // 9728 B; A bf16 [q][k] / [q][c]
  const int t    = threadIdx.x;
  const int grp  = blockIdx.x >> 11;
  const int id   = blockIdx.x & 2047;
  const int b    = id >> 9;
  const int q0   = (id & 511) * 32;
  const int wv   = t >> 6;
  const int lane = t & 63;
  const int li   = lane & 15, quad = lane >> 4;

  // stage A (all 128 k): src[k][q] fp32 -> a_s[q][k] bf16, k-pairs packed
  const float* Ab = (grp ? ext : nbr) + (size_t)b * C * HWn + q0;
#pragma unroll
  for (int it = 0; it < 2; ++it) {
    int idx = t + 256 * it;
    int kp  = idx >> 3;              // k-pair 0..63
    int q4  = (idx & 7) * 4;         // q group of 4
    float4 fa = *(const float4*)(Ab + (size_t)(2 * kp) * HWn + q4);
    float4 fb = *(const float4*)(Ab + (size_t)(2 * kp + 1) * HWn + q4);
    const float* pa = &fa.x; const float* pb = &fb.x;
#pragma unroll
    for (int j = 0; j < 4; ++j)
      *(unsigned*)&a_s[(q4 + j) * 152 + 2 * kp] = pack2bf(pa[j], pb[j]);
  }
  __syncthreads();

  const int mt = wv & 1;             // m-tile (q rows 16*mt..)

  if (grp == 0) {
    // ---- val GEMM: (32 q x 128 k) @ wval_t (128 c x 128 k)
    //      16 jobs = 4 waves x (1 m-tile x 4 n-tiles)
    const int ng = (wv >> 1) * 4;
    f32x4 acc[4];
#pragma unroll
    for (int i = 0; i < 4; ++i) acc[i] = (f32x4){0.f, 0.f, 0.f, 0.f};

#pragma unroll 1
    for (int ck = 0; ck < 4; ++ck) {
      short8 af = *(const short8*)&a_s[(16 * mt + li) * 152 + ck * 32 + quad * 8];
#pragma unroll
      for (int i = 0; i < 4; ++i) {
        short8 bfr = *(const short8*)(wval_t + (size_t)(16 * (ng + i) + li) * 128 +
                                      ck * 32 + quad * 8);
        acc[i] = __builtin_amdgcn_mfma_f32_16x16x32_bf16(af, bfr, acc[i], 0, 0, 0);
      }
    }
    __syncthreads();                 // a_s reads done; reuse as [q][c] bf16

    // epilogue: +bias, C-layout -> a_s[q][c]
#pragma unroll
    for (int i = 0; i < 4; ++i) {
      int c = 16 * (ng + i) + li;
      float bias = bv[c];
#pragma unroll
      for (int reg = 0; reg < 4; ++reg) {
        int q = mt * 16 + quad * 4 + reg;
        a_s[q * 152 + c] = (unsigned short)f2bf(acc[i][reg] + bias);
      }
    }
    __syncthreads();

    // coalesced head-plane store: thread (qi, head)
    {
      const int qi = t & 31, hs = t >> 5;
      uint4 v0 = *(const uint4*)&a_s[qi * 152 + 16 * hs];
      uint4 v1 = *(const uint4*)&a_s[qi * 152 + 16 * hs + 8];
      unsigned short* d = val + ((size_t)(b * NH + hs) * HWn + q0 + qi) * 16;
      *(uint4*)d = v0; *(uint4*)(d + 8) = v1;
    }
  } else {
    // ---- logits GEMM: (32 q x 128 k) @ wcat_t (192 cols x 128 k)
    //      24 jobs = 4 waves x (1 m-tile x 6 n-tiles)
    const int nset = wv >> 1;
    f32x4 lacc[6];
#pragma unroll
    for (int i = 0; i < 6; ++i) lacc[i] = (f32x4){0.f, 0.f, 0.f, 0.f};

#pragma unroll 1
    for (int ck = 0; ck < 4; ++ck) {
      short8 af = *(const short8*)&a_s[(16 * mt + li) * 152 + ck * 32 + quad * 8];
#pragma unroll
      for (int i = 0; i < 6; ++i) {
        int n = nset * 6 + i;
        short8 bfr = *(const short8*)(wcat_t + (size_t)(16 * n + li) * 128 +
                                      ck * 32 + quad * 8);
        lacc[i] = __builtin_amdgcn_mfma_f32_16x16x32_bf16(af, bfr, lacc[i], 0, 0, 0);
      }
    }

    // +bias, store raw logits from C-layout (16-lane 64B segments)
#pragma unroll
    for (int i = 0; i < 6; ++i) {
      int col = 16 * (nset * 6 + i) + li;
      float bias = (col < 128) ? boff[col] : battn[col - 128];
#pragma unroll
      for (int reg = 0; reg < 4; ++reg) {
        int q = mt * 16 + quad * 4 + reg;
        proj[(size_t)(b * HWn + q0 + q) * 192 + col] = lacc[i][reg] + bias;
      }
    }
  }
}

// K2: gather + MFMA out-projection (R9/R15 verbatim — at its
// scattered-request service-rate floor).
// VGPR history: R7 full unroll -> 164 VGPR (hoisted B-loads), Occ 11%;
// R8 unroll1+bounds(256,4) -> 64-tier spill; R9 unroll1, no bounds clause
// -> 120 VGPR, no spill. Policy: never use the min-waves clause; control
// pressure at the source.
__global__ __launch_bounds__(256) void gather_out_kernel(
    const float* __restrict__ flow, const float* __restrict__ proj,
    const unsigned short* __restrict__ val,
    const unsigned short* __restrict__ wout_t, const float* __restrict__ bout,
    float* __restrict__ out) {
  __shared__ float smem[128 * 33];            // 16896 B (c_s view)
  unsigned short* a_s2 = (unsigned short*)smem;  // [32][136] bf16, 8704 B
  float* c_s = smem;                          // [128][33] fp32

  const int t  = threadIdx.x;
  const int qi = t & 31;               // pixel within tile
  const int r  = t >> 5;               // head 0..7

  const int blk  = blockIdx.x;
  const int lin  = (blk & 7) * 256 + (blk >> 3);  // XCD swizzle (2048 % 8 == 0)
  const int b    = lin >> 9;
  const int tile = lin & 511;
  const int x0   = (tile & 7) * 16;
  const int y0   = (tile >> 3) * 2;
  const int x    = x0 + (qi & 15);
  const int y    = y0 + (qi >> 4);

  // ---- logits -> offsets / attention (in-thread epilogues), head r only
  const float* pp = proj + (size_t)(b * HWn + y * W + x) * 192;
  float offa[16];
  float atta[8];
#pragma unroll
  for (int j4 = 0; j4 < 4; ++j4) {
    float4 v = *(const float4*)(pp + 16 * r + 4 * j4);
    offa[4 * j4 + 0] = 10.f * fast_tanh(v.x);
    offa[4 * j4 + 1] = 10.f * fast_tanh(v.y);
    offa[4 * j4 + 2] = 10.f * fast_tanh(v.z);
    offa[4 * j4 + 3] = 10.f * fast_tanh(v.w);
  }
#pragma unroll
  for (int j4 = 0; j4 < 2; ++j4) {
    float4 v = *(const float4*)(pp + 128 + 8 * r + 4 * j4);
    atta[4 * j4 + 0] = v.x; atta[4 * j4 + 1] = v.y;
    atta[4 * j4 + 2] = v.z; atta[4 * j4 + 3] = v.w;
  }
  {
    float m = atta[0];
#pragma unroll
    for (int p = 1; p < 8; ++p) m = fmaxf(m, atta[p]);
    float s = 0.f;
#pragma unroll
    for (int p = 0; p < 8; ++p) { float ev = __expf(atta[p] - m); atta[p] = ev; s += ev; }
    float inv = 1.f / s;
#pragma unroll
    for (int p = 0; p < 8; ++p) atta[p] *= inv;
  }

  // ---- bilinear gather from bf16 head plane r
  const float xb = (float)x + flow[(size_t)b * 2 * HWn + y * W + x];
  const float yb = (float)y + flow[((size_t)b * 2 + 1) * HWn + y * W + x];

  float agg[16];
#pragma unroll
  for (int j = 0; j < 16; ++j) agg[j] = 0.f;
  const unsigned short* valh =
      val + ((size_t)b * NH + r) * HWn * 16;

#pragma unroll
  for (int p = 0; p < 8; ++p) {
    float sx = xb + offa[2 * p];
    float sy = yb + offa[2 * p + 1];
    float x0f = floorf(sx), y0f = floorf(sy);
    float wx = sx - x0f, wy = sy - y0f;
    int ix0 = (int)x0f, iy0 = (int)y0f;
    int ix1 = ix0 + 1,  iy1 = iy0 + 1;
    float aw  = atta[p];
    float w00 = aw * (1.f - wx) * (1.f - wy);
    float w10 = aw * wx * (1.f - wy);
    float w01 = aw * (1.f - wx) * wy;
    float w11 = aw * wx * wy;
    if ((unsigned)ix0 >= (unsigned)W) { w00 = 0.f; w01 = 0.f; }
    if ((unsigned)ix1 >= (unsigned)W) { w10 = 0.f; w11 = 0.f; }
    if ((unsigned)iy0 >= (unsigned)H) { w00 = 0.f; w10 = 0.f; }
    if ((unsigned)iy1 >= (unsigned)H) { w01 = 0.f; w11 = 0.f; }
    int x0c = min(max(ix0, 0), W - 1);
    int x1c = min(max(ix1, 0), W - 1);
    int y0c = min(max(iy0, 0), H - 1);
    int y1c = min(max(iy1, 0), H - 1);
    const unsigned short* c00 = valh + (size_t)(y0c * W + x0c) * 16;
    const unsigned short* c10 = valh + (size_t)(y0c * W + x1c) * 16;
    const unsigned short* c01 = valh + (size_t)(y1c * W + x0c) * 16;
    const unsigned short* c11 = valh + (size_t)(y1c * W + x1c) * 16;
#pragma unroll
    for (int cn = 0; cn < 4; ++cn) {
      const unsigned short* cp = (cn == 0) ? c00 : (cn == 1) ? c10
                                : (cn == 2) ? c01 : c11;
      float wgt = (cn == 0) ? w00 : (cn == 1) ? w10 : (cn == 2) ? w01 : w11;
      uint4 ga = ((const uint4*)cp)[0];
      uint4 gb = ((const uint4*)cp)[1];
      unsigned gs[8] = {ga.x, ga.y, ga.z, ga.w, gb.x, gb.y, gb.z, gb.w};
#pragma unroll
      for (int i = 0; i < 8; ++i) {
        float lo = __uint_as_float(gs[i] << 16);
        float hi = __uint_as_float(gs[i] & 0xFFFF0000u);
        agg[2 * i]     += wgt * lo;
        agg[2 * i + 1] += wgt * hi;
      }
    }
  }

  // ---- agg -> bf16 A-tile [32 px][136] (row qi, cols 16r..16r+15)
  {
    unsigned pk[8];
#pragma unroll
    for (int j = 0; j < 8; ++j) pk[j] = pack2bf(agg[2 * j], agg[2 * j + 1]);
    uint4* dst = (uint4*)&a_s2[qi * 136 + 16 * r];
    dst[0] = make_uint4(pk[0], pk[1], pk[2], pk[3]);
    dst[1] = make_uint4(pk[4], pk[5], pk[6], pk[7]);
  }
  __syncthreads();

  // ---- MFMA out-projection: (32 x 128) @ (128 x 128)
  const int lane = t & 63;
  const int li   = lane & 15, quad = lane >> 4;
  const int wv   = t >> 6;
  const int mt   = wv & 1;             // m-tile (q rows 16*mt..)
  const int ng   = (wv >> 1) * 4;      // n-tile base (4 tiles per wave)

  f32x4 acc[4];
#pragma unroll
  for (int i = 0; i < 4; ++i) acc[i] = (f32x4){0.f, 0.f, 0.f, 0.f};

#pragma unroll 1
  for (int ks = 0; ks < 4; ++ks) {
    short8 af = *(const short8*)&a_s2[(mt * 16 + li) * 136 + ks * 32 + quad * 8];
#pragma unroll
    for (int i = 0; i < 4; ++i) {
      short8 bfr = *(const short8*)(wout_t + (size_t)(16 * (ng + i) + li) * 128 +
                                    ks * 32 + quad * 8);
      acc[i] = __builtin_amdgcn_mfma_f32_16x16x32_bf16(af, bfr, acc[i], 0, 0, 0);
    }
  }
  __syncthreads();                     // all A reads done; reuse smem as c_s

  // ---- +bias, C-layout -> c_s[c][q] (padded stride 33)
#pragma unroll
  for (int i = 0; i < 4; ++i) {
    int c = 16 * (ng + i) + li;
    float bias = bout[c];
#pragma unroll
    for (int reg = 0; reg < 4; ++reg) {
      int q = mt * 16 + quad * 4 + reg;
      c_s[c * 33 + q] = acc[i][reg] + bias;
    }
  }
  __syncthreads();

  // stores: per channel, lanes cover the 16x2 tile (2 x 64B row segments)
  float* ob = out + (size_t)b * C * HWn + y * W + x;
#pragma unroll
  for (int j = 0; j < 16; ++j)
    ob[(size_t)(16 * r + j) * HWn] = c_s[(16 * r + j) * 33 + qi];
}

extern "C" void kernel_launch(void* const* d_in, const int* in_sizes, int n_in,
                              void* d_out, int out_size, void* d_ws, size_t ws_size,
                              hipStream_t stream) {
  const float* nbr   = (const float*)d_in[0];
  const float* extf  = (const float*)d_in[1];
  const float* flow  = (const float*)d_in[2];
  const float* Woff  = (const float*)d_in[3];
  const float* boff  = (const float*)d_in[4];
  const float* Wattn = (const float*)d_in[5];
  const float* battn = (const float*)d_in[6];
  const float* Wval  = (const float*)d_in[7];
  const float* bval  = (const float*)d_in[8];
  const float* Wout  = (const float*)d_in[9];
  const float* bout  = (const float*)d_in[10];
  float* outp = (float*)d_out;

  // ws layout: val bf16 16.78 MB | wcat_t 48 KB | wval_t 32 KB | wout_t 32 KB
  //            | proj 50.3 MB  -> total ~67.3 MB
  unsigned short* val    = (unsigned short*)d_ws;
  unsigned short* wcat_t = val + (size_t)B * NH * HWn * 16;
  unsigned short* wval_t = wcat_t + 192 * 128;
  unsigned short* wout_t = wval_t + 128 * 128;
  float*          proj   = (float*)(wout_t + 128 * 128);

  prep_weights_kernel<<<dim3(2), dim3(256), 0, stream>>>(
      Woff, Wattn, Wval, Wout, wcat_t, wval_t, wout_t);
  gemm_kernel<<<dim3(4096), dim3(256), 0, stream>>>(
      nbr, extf, wval_t, bval, wcat_t, boff, battn, val, proj);
  gather_out_kernel<<<dim3(2048), dim3(256), 0, stream>>>(
      flow, proj, val, wout_t, bout, outp);
}

// Round 13
// 222.888 us; speedup vs baseline: 1.1129x; 1.1129x over previous
//
#include <hip/hip_runtime.h>
#include <math.h>

namespace {
constexpr int B   = 4;
constexpr int C   = 128;
constexpr int H   = 128;
constexpr int W   = 128;
constexpr int HWn = H * W;           // 16384
constexpr int NH  = 8;
}

using short8 = __attribute__((ext_vector_type(8))) short;
using f32x4  = __attribute__((ext_vector_type(4))) float;

__device__ __forceinline__ float fast_tanh(float x) {
  float e = __expf(2.f * x);
  return 1.f - 2.f / (e + 1.f);
}
__device__ __forceinline__ unsigned f2bf(float f) {  // RNE bf16 bits
  unsigned u = __float_as_uint(f);
  return (u + 0x7FFFu + ((u >> 16) & 1u)) >> 16;
}
__device__ __forceinline__ unsigned pack2bf(float a, float b) {
  return f2bf(a) | (f2bf(b) << 16);
}

// ---------------------------------------------------------------------------
// R17 = R15 (= R9) verbatim — final configuration.
// Session ledger: R9/R15 reproduced at 223.7/224.4 us. All structural
// variants since returned <=0: proj-fusion (wash), light K1 x2 (R16: +24 us,
// wcat_t 48 KB > 32 KiB L1 thrash; stage B in LDS for throughput GEMMs),
// channel-split (occupancy x2, time unchanged), val_pair line packing
// (footprint > L2, regression). K2 is at its scattered-request service-rate
// floor (~33.5M 16 B line-requests, ~55-60 us TA service); occupancy and
// line-count levers both proven null. This is the practical floor.
// ---------------------------------------------------------------------------

// Prep: bf16 transposed weights in ws.
//   wcat_t[192][128]: rows 0..127 = Woff cols, 128..191 = Wattn cols
//   wval_t[128][128], wout_t[128][128] (wout_t[n][k] = Wout[k][n])
__global__ __launch_bounds__(256) void prep_weights_kernel(
    const float* __restrict__ Woff, const float* __restrict__ Wattn,
    const float* __restrict__ Wval, const float* __restrict__ Wout,
    unsigned short* __restrict__ wcat_t, unsigned short* __restrict__ wval_t,
    unsigned short* __restrict__ wout_t) {
  int row = blockIdx.x * 256 + threadIdx.x;
  if (row >= 448) return;
  const float* src; int ldn; int col; unsigned short* dst;
  if (row < 192) {
    if (row < 128) { src = Woff; ldn = 128; col = row; }
    else           { src = Wattn; ldn = 64; col = row - 128; }
    dst = wcat_t + row * 128;
  } else if (row < 320) {
    src = Wval; ldn = 128; col = row - 192; dst = wval_t + (row - 192) * 128;
  } else {
    src = Wout; ldn = 128; col = row - 320; dst = wout_t + (row - 320) * 128;
  }
  for (int k0 = 0; k0 < 128; k0 += 8) {
    unsigned pk[4];
#pragma unroll
    for (int j = 0; j < 4; ++j)
      pk[j] = pack2bf(src[(k0 + 2 * j) * ldn + col],
                      src[(k0 + 2 * j + 1) * ldn + col]);
    *(uint4*)(dst + k0) = make_uint4(pk[0], pk[1], pk[2], pk[3]);
  }
}

// K1: both input GEMMs via MFMA 16x16x32 bf16. 64-q strips.
//   grp0 (blocks 0..1023):    val[b][h][q][16] bf16  = nbr^T @ Wval + bval
//   grp1 (blocks 1024..2047): proj[b][q][0:192] fp32 = ext^T @ [Woff|Wattn]
__global__ __launch_bounds__(256) void gemm_kernel(
    const float* __restrict__ nbr, const float* __restrict__ ext,
    const unsigned short* __restrict__ wval_t,
    const float* __restrict__ bv,
    const unsigned short* __restrict__ wcat_t,
    const float* __restrict__ boff, const float* __restrict__ battn,
    unsigned short* __restrict__ val, float* __restrict__ proj) {
  __shared__ unsigned short a_s[64 * 152];   // 19456 B; A bf16 [q][k]
  __shared__ unsigned short b_s[192 * 40];   // 15360 B; B chunk [n][32k]
  const int t    = threadIdx.x;
  const int grp  = blockIdx.x >> 10;
  const int id   = blockIdx.x & 1023;
  const int b    = id >> 8;
  const int q0   = (id & 255) * 64;
  const int wv   = t >> 6;
  const int lane = t & 63;
  const int li   = lane & 15, quad = lane >> 4;

  // stage A (all 128 k): src[k][q] fp32 -> a_s[q][k] bf16, k-pairs packed
  const float* Ab = (grp ? ext : nbr) + (size_t)b * C * HWn + q0;
#pragma unroll
  for (int it = 0; it < 4; ++it) {
    int idx = t + 256 * it;
    int kp  = idx >> 4;
    int q4  = (idx & 15) * 4;
    float4 fa = *(const float4*)(Ab + (size_t)(2 * kp) * HWn + q4);
    float4 fb = *(const float4*)(Ab + (size_t)(2 * kp + 1) * HWn + q4);
    const float* pa = &fa.x; const float* pb = &fb.x;
#pragma unroll
    for (int j = 0; j < 4; ++j)
      *(unsigned*)&a_s[(q4 + j) * 152 + 2 * kp] = pack2bf(pa[j], pb[j]);
  }

  if (grp == 0) {
    // ------------------------- val GEMM: 64q x 128c -----------------------
    f32x4 acc[8];
#pragma unroll
    for (int n = 0; n < 8; ++n) acc[n] = (f32x4){0.f, 0.f, 0.f, 0.f};

    for (int ck = 0; ck < 4; ++ck) {
      __syncthreads();
#pragma unroll
      for (int it = 0; it < 2; ++it) {
        int idx = t + 256 * it;
        int n = idx >> 2, seg = idx & 3;
        *(uint4*)&b_s[n * 40 + seg * 8] =
            *(const uint4*)(wval_t + n * 128 + ck * 32 + seg * 8);
      }
      __syncthreads();
      short8 af = *(const short8*)&a_s[(16 * wv + li) * 152 + ck * 32 + quad * 8];
#pragma unroll
      for (int n = 0; n < 8; ++n) {
        short8 bfr = *(const short8*)&b_s[(16 * n + li) * 40 + quad * 8];
        acc[n] = __builtin_amdgcn_mfma_f32_16x16x32_bf16(af, bfr, acc[n], 0, 0, 0);
      }
    }

    // epilogue: +bias, C-layout -> a_s[q][c] bf16, coalesced head-plane store
    __syncthreads();
#pragma unroll
    for (int n = 0; n < 8; ++n) {
      float bias = bv[16 * n + li];
#pragma unroll
      for (int reg = 0; reg < 4; ++reg) {
        int q = 16 * wv + 4 * quad + reg;
        a_s[q * 152 + 16 * n + li] = (unsigned short)f2bf(acc[n][reg] + bias);
      }
    }
    __syncthreads();
    {
      const int qi = t & 63, r = t >> 6;
      uint4 v0 = *(const uint4*)&a_s[qi * 152 + 32 * r];
      uint4 v1 = *(const uint4*)&a_s[qi * 152 + 32 * r + 8];
      uint4 v2 = *(const uint4*)&a_s[qi * 152 + 32 * r + 16];
      uint4 v3 = *(const uint4*)&a_s[qi * 152 + 32 * r + 24];
      unsigned short* d0 = val + ((size_t)(b * NH + 2 * r) * HWn + q0 + qi) * 16;
      unsigned short* d1 = val + ((size_t)(b * NH + 2 * r + 1) * HWn + q0 + qi) * 16;
      *(uint4*)d0 = v0; *(uint4*)(d0 + 8) = v1;
      *(uint4*)d1 = v2; *(uint4*)(d1 + 8) = v3;
    }
  } else {
    // --------------------- off/attn logits GEMM: 64q x 192 ----------------
    f32x4 acc[12];
#pragma unroll
    for (int n = 0; n < 12; ++n) acc[n] = (f32x4){0.f, 0.f, 0.f, 0.f};

    for (int ck = 0; ck < 4; ++ck) {
      __syncthreads();
#pragma unroll
      for (int it = 0; it < 3; ++it) {
        int idx = t + 256 * it;
        int n = idx >> 2, seg = idx & 3;
        *(uint4*)&b_s[n * 40 + seg * 8] =
            *(const uint4*)(wcat_t + n * 128 + ck * 32 + seg * 8);
      }
      __syncthreads();
      short8 af = *(const short8*)&a_s[(16 * wv + li) * 152 + ck * 32 + quad * 8];
#pragma unroll
      for (int n = 0; n < 12; ++n) {
        short8 bfr = *(const short8*)&b_s[(16 * n + li) * 40 + quad * 8];
        acc[n] = __builtin_amdgcn_mfma_f32_16x16x32_bf16(af, bfr, acc[n], 0, 0, 0);
      }
    }

    // +bias, store raw logits from C-layout (16-lane 64B segments)
#pragma unroll
    for (int n = 0; n < 12; ++n) {
      int col = 16 * n + li;
      float bias = (col < 128) ? boff[col] : battn[col - 128];
#pragma unroll
      for (int reg = 0; reg < 4; ++reg) {
        int q = 16 * wv + 4 * quad + reg;
        proj[(size_t)(b * HWn + q0 + q) * 192 + col] = acc[n][reg] + bias;
      }
    }
  }
}

// K2: gather + MFMA out-projection (R9 structure, at its scattered-request
// service-rate floor).
// VGPR history: R7 full unroll -> 164 VGPR (hoisted B-loads), Occ 11%;
// R8 unroll1+bounds(256,4) -> 64-tier spill; R9 unroll1, no bounds clause
// -> 120 VGPR, no spill. Policy: never use the min-waves clause; control
// pressure at the source.
__global__ __launch_bounds__(256) void gather_out_kernel(
    const float* __restrict__ flow, const float* __restrict__ proj,
    const unsigned short* __restrict__ val,
    const unsigned short* __restrict__ wout_t, const float* __restrict__ bout,
    float* __restrict__ out) {
  __shared__ float smem[128 * 33];            // 16896 B (c_s view)
  unsigned short* a_s2 = (unsigned short*)smem;  // [32][136] bf16, 8704 B
  float* c_s = smem;                          // [128][33] fp32

  const int t  = threadIdx.x;
  const int qi = t & 31;               // pixel within tile
  const int r  = t >> 5;               // head 0..7

  const int blk  = blockIdx.x;
  const int lin  = (blk & 7) * 256 + (blk >> 3);  // XCD swizzle (2048 % 8 == 0)
  const int b    = lin >> 9;
  const int tile = lin & 511;
  const int x0   = (tile & 7) * 16;
  const int y0   = (tile >> 3) * 2;
  const int x    = x0 + (qi & 15);
  const int y    = y0 + (qi >> 4);

  // ---- logits -> offsets / attention (in-thread epilogues), head r only
  const float* pp = proj + (size_t)(b * HWn + y * W + x) * 192;
  float offa[16];
  float atta[8];
#pragma unroll
  for (int j4 = 0; j4 < 4; ++j4) {
    float4 v = *(const float4*)(pp + 16 * r + 4 * j4);
    offa[4 * j4 + 0] = 10.f * fast_tanh(v.x);
    offa[4 * j4 + 1] = 10.f * fast_tanh(v.y);
    offa[4 * j4 + 2] = 10.f * fast_tanh(v.z);
    offa[4 * j4 + 3] = 10.f * fast_tanh(v.w);
  }
#pragma unroll
  for (int j4 = 0; j4 < 2; ++j4) {
    float4 v = *(const float4*)(pp + 128 + 8 * r + 4 * j4);
    atta[4 * j4 + 0] = v.x; atta[4 * j4 + 1] = v.y;
    atta[4 * j4 + 2] = v.z; atta[4 * j4 + 3] = v.w;
  }
  {
    float m = atta[0];
#pragma unroll
    for (int p = 1; p < 8; ++p) m = fmaxf(m, atta[p]);
    float s = 0.f;
#pragma unroll
    for (int p = 0; p < 8; ++p) { float ev = __expf(atta[p] - m); atta[p] = ev; s += ev; }
    float inv = 1.f / s;
#pragma unroll
    for (int p = 0; p < 8; ++p) atta[p] *= inv;
  }

  // ---- bilinear gather from bf16 head plane r
  const float xb = (float)x + flow[(size_t)b * 2 * HWn + y * W + x];
  const float yb = (float)y + flow[((size_t)b * 2 + 1) * HWn + y * W + x];

  float agg[16];
#pragma unroll
  for (int j = 0; j < 16; ++j) agg[j] = 0.f;
  const unsigned short* valh =
      val + ((size_t)b * NH + r) * HWn * 16;

#pragma unroll
  for (int p = 0; p < 8; ++p) {
    float sx = xb + offa[2 * p];
    float sy = yb + offa[2 * p + 1];
    float x0f = floorf(sx), y0f = floorf(sy);
    float wx = sx - x0f, wy = sy - y0f;
    int ix0 = (int)x0f, iy0 = (int)y0f;
    int ix1 = ix0 + 1,  iy1 = iy0 + 1;
    float aw  = atta[p];
    float w00 = aw * (1.f - wx) * (1.f - wy);
    float w10 = aw * wx * (1.f - wy);
    float w01 = aw * (1.f - wx) * wy;
    float w11 = aw * wx * wy;
    if ((unsigned)ix0 >= (unsigned)W) { w00 = 0.f; w01 = 0.f; }
    if ((unsigned)ix1 >= (unsigned)W) { w10 = 0.f; w11 = 0.f; }
    if ((unsigned)iy0 >= (unsigned)H) { w00 = 0.f; w10 = 0.f; }
    if ((unsigned)iy1 >= (unsigned)H) { w01 = 0.f; w11 = 0.f; }
    int x0c = min(max(ix0, 0), W - 1);
    int x1c = min(max(ix1, 0), W - 1);
    int y0c = min(max(iy0, 0), H - 1);
    int y1c = min(max(iy1, 0), H - 1);
    const unsigned short* c00 = valh + (size_t)(y0c * W + x0c) * 16;
    const unsigned short* c10 = valh + (size_t)(y0c * W + x1c) * 16;
    const unsigned short* c01 = valh + (size_t)(y1c * W + x0c) * 16;
    const unsigned short* c11 = valh + (size_t)(y1c * W + x1c) * 16;
#pragma unroll
    for (int cn = 0; cn < 4; ++cn) {
      const unsigned short* cp = (cn == 0) ? c00 : (cn == 1) ? c10
                                : (cn == 2) ? c01 : c11;
      float wgt = (cn == 0) ? w00 : (cn == 1) ? w10 : (cn == 2) ? w01 : w11;
      uint4 ga = ((const uint4*)cp)[0];
      uint4 gb = ((const uint4*)cp)[1];
      unsigned gs[8] = {ga.x, ga.y, ga.z, ga.w, gb.x, gb.y, gb.z, gb.w};
#pragma unroll
      for (int i = 0; i < 8; ++i) {
        float lo = __uint_as_float(gs[i] << 16);
        float hi = __uint_as_float(gs[i] & 0xFFFF0000u);
        agg[2 * i]     += wgt * lo;
        agg[2 * i + 1] += wgt * hi;
      }
    }
  }

  // ---- agg -> bf16 A-tile [32 px][136] (row qi, cols 16r..16r+15)
  {
    unsigned pk[8];
#pragma unroll
    for (int j = 0; j < 8; ++j) pk[j] = pack2bf(agg[2 * j], agg[2 * j + 1]);
    uint4* dst = (uint4*)&a_s2[qi * 136 + 16 * r];
    dst[0] = make_uint4(pk[0], pk[1], pk[2], pk[3]);
    dst[1] = make_uint4(pk[4], pk[5], pk[6], pk[7]);
  }
  __syncthreads();

  // ---- MFMA out-projection: (32 x 128) @ (128 x 128)
  const int lane = t & 63;
  const int li   = lane & 15, quad = lane >> 4;
  const int wv   = t >> 6;
  const int mt   = wv & 1;             // m-tile (q rows 16*mt..)
  const int ng   = (wv >> 1) * 4;      // n-tile base (4 tiles per wave)

  f32x4 acc[4];
#pragma unroll
  for (int i = 0; i < 4; ++i) acc[i] = (f32x4){0.f, 0.f, 0.f, 0.f};

#pragma unroll 1
  for (int ks = 0; ks < 4; ++ks) {
    short8 af = *(const short8*)&a_s2[(mt * 16 + li) * 136 + ks * 32 + quad * 8];
#pragma unroll
    for (int i = 0; i < 4; ++i) {
      short8 bfr = *(const short8*)(wout_t + (size_t)(16 * (ng + i) + li) * 128 +
                                    ks * 32 + quad * 8);
      acc[i] = __builtin_amdgcn_mfma_f32_16x16x32_bf16(af, bfr, acc[i], 0, 0, 0);
    }
  }
  __syncthreads();                     // all A reads done; reuse smem as c_s

  // ---- +bias, C-layout -> c_s[c][q] (padded stride 33)
#pragma unroll
  for (int i = 0; i < 4; ++i) {
    int c = 16 * (ng + i) + li;
    float bias = bout[c];
#pragma unroll
    for (int reg = 0; reg < 4; ++reg) {
      int q = mt * 16 + quad * 4 + reg;
      c_s[c * 33 + q] = acc[i][reg] + bias;
    }
  }
  __syncthreads();

  // stores: per channel, lanes cover the 16x2 tile (2 x 64B row segments)
  float* ob = out + (size_t)b * C * HWn + y * W + x;
#pragma unroll
  for (int j = 0; j < 16; ++j)
    ob[(size_t)(16 * r + j) * HWn] = c_s[(16 * r + j) * 33 + qi];
}

extern "C" void kernel_launch(void* const* d_in, const int* in_sizes, int n_in,
                              void* d_out, int out_size, void* d_ws, size_t ws_size,
                              hipStream_t stream) {
  const float* nbr   = (const float*)d_in[0];
  const float* extf  = (const float*)d_in[1];
  const float* flow  = (const float*)d_in[2];
  const float* Woff  = (const float*)d_in[3];
  const float* boff  = (const float*)d_in[4];
  const float* Wattn = (const float*)d_in[5];
  const float* battn = (const float*)d_in[6];
  const float* Wval  = (const float*)d_in[7];
  const float* bval  = (const float*)d_in[8];
  const float* Wout  = (const float*)d_in[9];
  const float* bout  = (const float*)d_in[10];
  float* outp = (float*)d_out;

  // ws layout: val bf16 16.78 MB | wcat_t 48 KB | wval_t 32 KB | wout_t 32 KB
  //            | proj 50.3 MB  -> total ~67.3 MB
  unsigned short* val    = (unsigned short*)d_ws;
  unsigned short* wcat_t = val + (size_t)B * NH * HWn * 16;
  unsigned short* wval_t = wcat_t + 192 * 128;
  unsigned short* wout_t = wval_t + 128 * 128;
  float*          proj   = (float*)(wout_t + 128 * 128);

  prep_weights_kernel<<<dim3(2), dim3(256), 0, stream>>>(
      Woff, Wattn, Wval, Wout, wcat_t, wval_t, wout_t);
  gemm_kernel<<<dim3(2048), dim3(256), 0, stream>>>(
      nbr, extf, wval_t, bval, wcat_t, boff, battn, val, proj);
  gather_out_kernel<<<dim3(2048), dim3(256), 0, stream>>>(
      flow, proj, val, wout_t, bout, outp);
}